// Round 7
// baseline (29.904 us; speedup 1.0000x reference)
//
#include <hip/hip_runtime.h>

#define TILE 16
#define PPT 64

#if __has_builtin(__builtin_amdgcn_exp2f)
#define EXP2F(x) __builtin_amdgcn_exp2f(x)
#else
#define EXP2F(x) exp2f(x)
#endif

// Robustly read a small positive integer scalar that may have been stored
// as int32 or float32 bits.
__device__ __forceinline__ int read_dim(const int* p) {
    int v = *p;
    if (v >= TILE && v <= 65536 && (v % TILE) == 0) return v;
    float f = __int_as_float(v);
    return (int)f;
}

struct Acc {
    float T, Tg, r, g, b, d;
    int cnt, last;
};

// One compositing step (log2 domain, telescoping weight, Tg==0 sentinel
// for saturation; T frozen at last contribution).
__device__ __forceinline__ void composite(
    float dy, float q, float base, float pcc, const float4& C, int jp1,
    Acc& a)
{
    const float e     = fmaf(fmaf(pcc, dy, q), dy, base);
    const bool  vis   = e >= -7.9943533f;            // log2(1/255)
    const float alpha = EXP2F(e);
    const float one_m = fmaxf(1.0f - alpha, 0.01f);  // = 1 - min(alpha,0.99)
    const float Tone  = a.Tg * one_m;
    const bool  contrib = vis && (Tone >= 1e-4f);
    const float w = contrib ? (a.Tg - Tone) : 0.0f;
    a.r = fmaf(w, C.x, a.r);  a.g = fmaf(w, C.y, a.g);
    a.b = fmaf(w, C.z, a.b);  a.d = fmaf(w, C.w, a.d);
    a.cnt += contrib;
    a.last = contrib ? jp1 : a.last;
    a.T  = contrib ? Tone : a.T;
    a.Tg = vis ? (contrib ? Tone : 0.0f) : a.Tg;
}

// Full 64-point compositing for this thread's two pixels (rows pv0, pv0+8,
// same column -> dx/q/base shared per point).
__device__ __forceinline__ void run_pass(
    float pix_u, float pix_v0,
    const float4* __restrict__ sA, const float2* __restrict__ sB,
    const float4* __restrict__ sC,
    Acc& a0, Acc& a1)
{
    a0 = {1.0f, 1.0f, 0.f, 0.f, 0.f, 0.f, 0, 0};
    a1 = {1.0f, 1.0f, 0.f, 0.f, 0.f, 0.f, 0, 0};
    for (int c8 = 0; c8 < PPT / 8; ++c8) {
        #pragma unroll
        for (int k = 0; k < 8; ++k) {
            const int j = c8 * 8 + k;
            const float4 A = sA[j];   // wave-uniform broadcast
            const float2 B = sB[j];
            const float4 C = sC[j];
            const float dx   = pix_u - A.x;
            const float q    = B.x * dx;                 // pb*dx
            const float base = fmaf(A.z * dx, dx, B.y);  // pa*dx^2 + lal
            const float dy0  = pix_v0 - A.y;
            composite(dy0,        q, base, A.w, C, j + 1, a0);
            composite(dy0 + 8.0f, q, base, A.w, C, j + 1, a1);
        }
        if (__all((a0.Tg == 0.0f) && (a1.Tg == 0.0f))) break;
    }
}

// DIAGNOSTIC build: the whole compositing runs TWICE (pass inputs made
// opaque with inline asm so the compiler cannot CSE the two passes), and
// outputs are the bit-exact average. Measures dur = floor + 2*K to
// decompose measurement floor vs. real kernel compute K.
__global__ __launch_bounds__(128, 2) void gsplat_raster_kernel(
    const float* __restrict__ point_uv,          // (N,2)
    const float* __restrict__ point_conic,       // (N,3)
    const float* __restrict__ point_alpha,       // (N,)
    const float* __restrict__ point_color,       // (N,3)
    const float* __restrict__ point_depth,       // (N,)
    const int*   __restrict__ tile_point_indices,// (NT,PPT)
    const int*   __restrict__ cam_h_p,
    const int*   __restrict__ cam_w_p,
    float* __restrict__ out)
{
    const int t = blockIdx.x;
    const int p = threadIdx.x;   // 0..127

    const int W  = read_dim(cam_w_p);
    const int H  = read_dim(cam_h_p);
    const int TU = W / TILE;
    const int n_pix = H * W;

    // sA = {u, v, -0.5*log2e*a, -0.5*log2e*c}; sB = {-log2e*b, log2(alpha)};
    // sC = {r, g, b, depth}
    __shared__ float4 sA[PPT];
    __shared__ float2 sB[PPT];
    __shared__ float4 sC[PPT];

    const float L2E = 1.4426950408889634f;
    if (p < PPT) {                       // wave 0: geometry side
        const int gi = tile_point_indices[t * PPT + p];
        const float2 uv = ((const float2*)point_uv)[gi];
        sA[p] = make_float4(uv.x, uv.y,
                            -0.5f * L2E * point_conic[gi * 3 + 0],
                            -0.5f * L2E * point_conic[gi * 3 + 2]);
        sB[p] = make_float2(-L2E * point_conic[gi * 3 + 1],
                            __log2f(point_alpha[gi]));
    } else {                             // wave 1: color/depth side
        const int q  = p - PPT;
        const int gi = tile_point_indices[t * PPT + q];
        sC[q] = make_float4(point_color[gi * 3 + 0],
                            point_color[gi * 3 + 1],
                            point_color[gi * 3 + 2],
                            point_depth[gi]);
    }
    __syncthreads();

    const int tu  = t % TU;
    const int tv  = t / TU;
    const int pu  = p % TILE;
    const int pv0 = p / TILE;      // rows 0..7 (second pixel = +8)
    const float pix_u  = (float)(tu * TILE + pu) + 0.5f;
    const float pix_v0 = (float)(tv * TILE + pv0) + 0.5f;

    // ---- pass X (opaque coords; cannot CSE with pass Y) ----
    float ux = pix_u, vx = pix_v0;
    asm volatile("" : "+v"(ux), "+v"(vx));
    Acc x0, x1;
    run_pass(ux, vx, sA, sB, sC, x0, x1);

    // ---- pass Y ----
    float uy = pix_u, vy = pix_v0;
    asm volatile("" : "+v"(uy), "+v"(vy));
    Acc y0, y1;
    run_pass(uy, vy, sA, sB, sC, y0, y1);

    // ---- bit-exact average of the two identical passes ----
    const int c    = tu * TILE + pu;
    const int row0 = tv * TILE + pv0;
    const int pix0 = row0 * W + c;
    const int pix1 = pix0 + 8 * W;

    const float T0 = 0.5f * (x0.T + y0.T);
    const float T1 = 0.5f * (x1.T + y1.T);
    const float norm0 = 1.0f - T0;   // == sum(w) by telescoping
    const float norm1 = 1.0f - T1;

    out[pix0 * 3 + 0] = 0.5f * (x0.r + y0.r);
    out[pix0 * 3 + 1] = 0.5f * (x0.g + y0.g);
    out[pix0 * 3 + 2] = 0.5f * (x0.b + y0.b);
    out[n_pix * 3 + pix0] = (0.5f * (x0.d + y0.d)) / fmaxf(norm0, 1e-6f);
    out[n_pix * 4 + pix0] = norm0;
    out[n_pix * 5 + pix0] = (float)(t * PPT + ((x0.last + y0.last) >> 1));
    out[n_pix * 6 + pix0] = (float)((x0.cnt + y0.cnt) >> 1);

    out[pix1 * 3 + 0] = 0.5f * (x1.r + y1.r);
    out[pix1 * 3 + 1] = 0.5f * (x1.g + y1.g);
    out[pix1 * 3 + 2] = 0.5f * (x1.b + y1.b);
    out[n_pix * 3 + pix1] = (0.5f * (x1.d + y1.d)) / fmaxf(norm1, 1e-6f);
    out[n_pix * 4 + pix1] = norm1;
    out[n_pix * 5 + pix1] = (float)(t * PPT + ((x1.last + y1.last) >> 1));
    out[n_pix * 6 + pix1] = (float)((x1.cnt + y1.cnt) >> 1);
}

extern "C" void kernel_launch(void* const* d_in, const int* in_sizes, int n_in,
                              void* d_out, int out_size, void* d_ws, size_t ws_size,
                              hipStream_t stream) {
    const float* point_uv    = (const float*)d_in[0];
    const float* point_conic = (const float*)d_in[1];
    const float* point_alpha = (const float*)d_in[2];
    const float* point_color = (const float*)d_in[3];
    const float* point_depth = (const float*)d_in[4];
    const int*   tpi         = (const int*)d_in[5];
    const int*   cam_h       = (const int*)d_in[6];
    const int*   cam_w       = (const int*)d_in[7];

    const int NT = in_sizes[5] / PPT;  // number of tiles

    gsplat_raster_kernel<<<NT, 128, 0, stream>>>(
        point_uv, point_conic, point_alpha, point_color, point_depth,
        tpi, cam_h, cam_w, (float*)d_out);
}

// Round 8
// 18.455 us; speedup vs baseline: 1.6204x; 1.6204x over previous
//
#include <hip/hip_runtime.h>

#define TILE 16
#define PPT 64

#if __has_builtin(__builtin_amdgcn_exp2f)
#define EXP2F(x) __builtin_amdgcn_exp2f(x)
#else
#define EXP2F(x) exp2f(x)
#endif

// Robustly read a small positive integer scalar that may have been stored
// as int32 or float32 bits.
__device__ __forceinline__ int read_dim(const int* p) {
    int v = *p;
    if (v >= TILE && v <= 65536 && (v % TILE) == 0) return v;
    float f = __int_as_float(v);
    return (int)f;
}

struct Acc {
    float T, Tg, r, g, b, d;
    int cnt, last;
};

// One serial compositing step from precomputed (e, alpha). Formulas are
// bit-identical to the R6 kernel (keeps the near-threshold integer outputs
// stable). Tg==0 is the saturation sentinel; T freezes at last contribution;
// w telescopes so norm = 1 - T_final.
__device__ __forceinline__ void step(
    float e, float alpha, const float4& C, int jp1, Acc& a)
{
    const bool  vis   = e >= -7.9943533f;            // log2(1/255)
    const float one_m = fmaxf(1.0f - alpha, 0.01f);  // = 1 - min(alpha,0.99)
    const float Tone  = a.Tg * one_m;
    const bool  contrib = vis && (Tone >= 1e-4f);
    const float w = contrib ? (a.Tg - Tone) : 0.0f;
    a.r = fmaf(w, C.x, a.r);  a.g = fmaf(w, C.y, a.g);
    a.b = fmaf(w, C.z, a.b);  a.d = fmaf(w, C.w, a.d);
    a.cnt += contrib;
    a.last = contrib ? jp1 : a.last;
    a.T  = contrib ? Tone : a.T;
    a.Tg = vis ? (contrib ? Tone : 0.0f) : a.Tg;
}

// One block = one tile = 128 threads (2 waves); thread p composites pixels
// (pv0, pu) and (pv0+8, pu) — same column, sharing dx/q/base per point.
// SCHEDULE-FORCED: per 8-point group, ALL independent math (e, exp2) is
// computed into register arrays first (fully pipelined, no serial dep),
// then the two short per-pixel T-chains consume from registers. Break
// check only every 16 points (fewer basic-block scheduling barriers).
__global__ __launch_bounds__(128, 2) void gsplat_raster_kernel(
    const float* __restrict__ point_uv,          // (N,2)
    const float* __restrict__ point_conic,       // (N,3)
    const float* __restrict__ point_alpha,       // (N,)
    const float* __restrict__ point_color,       // (N,3)
    const float* __restrict__ point_depth,       // (N,)
    const int*   __restrict__ tile_point_indices,// (NT,PPT)
    const int*   __restrict__ cam_h_p,
    const int*   __restrict__ cam_w_p,
    float* __restrict__ out)
{
    const int t = blockIdx.x;
    const int p = threadIdx.x;   // 0..127

    const int W  = read_dim(cam_w_p);
    const int H  = read_dim(cam_h_p);
    const int TU = W / TILE;
    const int n_pix = H * W;

    // sA = {u, v, -0.5*log2e*a, -0.5*log2e*c}; sB = {-log2e*b, log2(alpha)};
    // sC = {r, g, b, depth}
    __shared__ float4 sA[PPT];
    __shared__ float2 sB[PPT];
    __shared__ float4 sC[PPT];

    const float L2E = 1.4426950408889634f;
    if (p < PPT) {                       // wave 0: geometry side
        const int gi = tile_point_indices[t * PPT + p];
        const float2 uv = ((const float2*)point_uv)[gi];
        sA[p] = make_float4(uv.x, uv.y,
                            -0.5f * L2E * point_conic[gi * 3 + 0],
                            -0.5f * L2E * point_conic[gi * 3 + 2]);
        sB[p] = make_float2(-L2E * point_conic[gi * 3 + 1],
                            __log2f(point_alpha[gi]));
    } else {                             // wave 1: color/depth side
        const int q  = p - PPT;
        const int gi = tile_point_indices[t * PPT + q];
        sC[q] = make_float4(point_color[gi * 3 + 0],
                            point_color[gi * 3 + 1],
                            point_color[gi * 3 + 2],
                            point_depth[gi]);
    }
    __syncthreads();

    const int tu  = t % TU;
    const int tv  = t / TU;
    const int pu  = p % TILE;
    const int pv0 = p / TILE;      // rows 0..7 (second pixel = +8)
    const float pix_u  = (float)(tu * TILE + pu) + 0.5f;
    const float pix_v0 = (float)(tv * TILE + pv0) + 0.5f;

    Acc a0 = {1.0f, 1.0f, 0.f, 0.f, 0.f, 0.f, 0, 0};
    Acc a1 = {1.0f, 1.0f, 0.f, 0.f, 0.f, 0.f, 0, 0};

    #pragma unroll 1
    for (int sg = 0; sg < PPT / 16; ++sg) {      // supergroups of 16 points
        #pragma unroll
        for (int h = 0; h < 2; ++h) {            // 2 groups of 8, same BB
            const int gb = sg * 16 + h * 8;

            // ---- phase 1: independent math into register arrays ----
            float  e0[8], e1[8], al0[8], al1[8];
            float4 C[8];
            #pragma unroll
            for (int k = 0; k < 8; ++k) {
                const int j = gb + k;
                const float4 A = sA[j];   // wave-uniform broadcast
                const float2 B = sB[j];
                C[k] = sC[j];
                const float dx   = pix_u - A.x;
                const float q    = B.x * dx;                 // pb*dx
                const float base = fmaf(A.z * dx, dx, B.y);  // pa*dx^2+lal
                const float dy0  = pix_v0 - A.y;
                const float dy1  = dy0 + 8.0f;
                e0[k] = fmaf(fmaf(A.w, dy0, q), dy0, base);
                e1[k] = fmaf(fmaf(A.w, dy1, q), dy1, base);
                al0[k] = EXP2F(e0[k]);
                al1[k] = EXP2F(e1[k]);
            }

            // ---- phase 2: serial chains from registers ----
            #pragma unroll
            for (int k = 0; k < 8; ++k) {
                const int jp1 = gb + k + 1;
                step(e0[k], al0[k], C[k], jp1, a0);
                step(e1[k], al1[k], C[k], jp1, a1);
            }
        }
        // exact skip: once Tg==0 for all lanes, remaining steps are no-ops
        if (__all((a0.Tg == 0.0f) && (a1.Tg == 0.0f))) break;
    }

    // ---- write outputs (image layout) ----
    const int c    = tu * TILE + pu;
    const int row0 = tv * TILE + pv0;
    const int pix0 = row0 * W + c;
    const int pix1 = pix0 + 8 * W;

    const float norm0 = 1.0f - a0.T;   // == sum(w) by telescoping
    const float norm1 = 1.0f - a1.T;

    out[pix0 * 3 + 0] = a0.r;
    out[pix0 * 3 + 1] = a0.g;
    out[pix0 * 3 + 2] = a0.b;
    out[n_pix * 3 + pix0] = a0.d / fmaxf(norm0, 1e-6f);
    out[n_pix * 4 + pix0] = norm0;
    out[n_pix * 5 + pix0] = (float)(t * PPT + a0.last);
    out[n_pix * 6 + pix0] = (float)a0.cnt;

    out[pix1 * 3 + 0] = a1.r;
    out[pix1 * 3 + 1] = a1.g;
    out[pix1 * 3 + 2] = a1.b;
    out[n_pix * 3 + pix1] = a1.d / fmaxf(norm1, 1e-6f);
    out[n_pix * 4 + pix1] = norm1;
    out[n_pix * 5 + pix1] = (float)(t * PPT + a1.last);
    out[n_pix * 6 + pix1] = (float)a1.cnt;
}

extern "C" void kernel_launch(void* const* d_in, const int* in_sizes, int n_in,
                              void* d_out, int out_size, void* d_ws, size_t ws_size,
                              hipStream_t stream) {
    const float* point_uv    = (const float*)d_in[0];
    const float* point_conic = (const float*)d_in[1];
    const float* point_alpha = (const float*)d_in[2];
    const float* point_color = (const float*)d_in[3];
    const float* point_depth = (const float*)d_in[4];
    const int*   tpi         = (const int*)d_in[5];
    const int*   cam_h       = (const int*)d_in[6];
    const int*   cam_w       = (const int*)d_in[7];

    const int NT = in_sizes[5] / PPT;  // number of tiles

    gsplat_raster_kernel<<<NT, 128, 0, stream>>>(
        point_uv, point_conic, point_alpha, point_color, point_depth,
        tpi, cam_h, cam_w, (float*)d_out);
}